// Round 3
// baseline (110.898 us; speedup 1.0000x reference)
//
#include <hip/hip_runtime.h>
#include <stdint.h>

typedef unsigned int u32;
typedef unsigned long long u64;
typedef unsigned short u16;
typedef unsigned char u8;

#define NPTS 8192
#define NTILES (32 * 33)

#define CAP 16           // row-major earlier-neighbor slots per point (packed u16x2)
#define OVFC 12          // overflow slots per point (16+12=28 = round-2-proven bound)
#define ZS NPTS          // neutral LDS slot, holds state==2 (SUPP)
#define ZZ (((u32)ZS << 16) | (u32)ZS)   // packed pair of ZS halfwords

// ---------------------------------------------------------------------------
// A: rank by counting, register-tiled 4 points/thread (unchanged core).
// Block 0 zeroes cnt | cnt_ovf (2*NPTS u32).
// ---------------------------------------------------------------------------
__global__ __launch_bounds__(1024) void k_rank(const float* __restrict__ coords,
                                               const float* __restrict__ scores,
                                               u32* __restrict__ sorted_id,
                                               float* __restrict__ sx,
                                               float* __restrict__ sy,
                                               float* __restrict__ ss,
                                               u32* __restrict__ zero_region) {
  __shared__ u32 skey[NPTS];
  __shared__ u32 part[16][4];
  int t = threadIdx.x, B = blockIdx.x;
  for (int k = t; k < NPTS; k += 1024) skey[k] = __float_as_uint(scores[k]);
  if (B == 0) {
    for (int k = t; k < 2 * NPTS; k += 1024) zero_region[k] = 0;
  }
  __syncthreads();

  int qd = t >> 7;        // quad 0..7 (4 points each)
  int s = t & 127;        // slice 0..127 (64 keys each)
  int p0 = B * 32 + qd * 4;
  int sp = B >> 1;        // the one slice containing this block's points
  u32 kp0 = skey[p0], kp1 = skey[p0 + 1], kp2 = skey[p0 + 2], kp3 = skey[p0 + 3];
  u32 c0 = 0, c1 = 0, c2 = 0, c3 = 0;
  const uint4* k4 = (const uint4*)skey;

  if (s != sp) {
    bool below = (s < sp);
    u32 a0 = below ? kp0 - 1u : kp0;  // >= via > (kp-1); kp==0 fixed below
    u32 a1 = below ? kp1 - 1u : kp1;
    u32 a2 = below ? kp2 - 1u : kp2;
    u32 a3 = below ? kp3 - 1u : kp3;
    int b4 = s << 4;
#pragma unroll 4
    for (int j = 0; j < 16; ++j) {
      int jj = (j + s) & 15;          // rotate across bank groups
      uint4 kv = k4[b4 + jj];
      c0 += (kv.x > a0) + (kv.y > a0) + (kv.z > a0) + (kv.w > a0);
      c1 += (kv.x > a1) + (kv.y > a1) + (kv.z > a1) + (kv.w > a1);
      c2 += (kv.x > a2) + (kv.y > a2) + (kv.z > a2) + (kv.w > a2);
      c3 += (kv.x > a3) + (kv.y > a3) + (kv.z > a3) + (kv.w > a3);
    }
    if (below) {  // underflow fixup: kp==0 means all 64 keys count as >=
      if (kp0 == 0) c0 += 64;
      if (kp1 == 0) c1 += 64;
      if (kp2 == 0) c2 += 64;
      if (kp3 == 0) c3 += 64;
    }
  } else {
    int q0 = s << 6;
    int mo = p0 - q0;  // 0..60, multiple of 4
    u32 a0 = kp0 - 1u, a1 = kp1 - 1u, a2 = kp2 - 1u, a3 = kp3 - 1u;
    for (int j = 0; j < mo; ++j) {       // q < p0: count >=
      u32 kq = skey[q0 + j];
      c0 += (kq > a0); c1 += (kq > a1); c2 += (kq > a2); c3 += (kq > a3);
    }
    if (kp0 == 0) c0 += mo;
    if (kp1 == 0) c1 += mo;
    if (kp2 == 0) c2 += mo;
    if (kp3 == 0) c3 += mo;
#pragma unroll
    for (int j2 = 0; j2 < 4; ++j2) {     // q in [p0, p0+4): exact tie logic
      int q = p0 + j2;
      u32 kq = skey[q];
      c0 += (kq > kp0) || (kq == kp0 && q < p0);
      c1 += (kq > kp1) || (kq == kp1 && q < p0 + 1);
      c2 += (kq > kp2) || (kq == kp2 && q < p0 + 2);
      c3 += (kq > kp3) || (kq == kp3 && q < p0 + 3);
    }
    for (int j = mo + 4; j < 64; ++j) {  // q > p_e: count >
      u32 kq = skey[q0 + j];
      c0 += (kq > kp0); c1 += (kq > kp1); c2 += (kq > kp2); c3 += (kq > kp3);
    }
  }

#pragma unroll
  for (int d = 1; d < 64; d <<= 1) {
    c0 += __shfl_xor(c0, d);
    c1 += __shfl_xor(c1, d);
    c2 += __shfl_xor(c2, d);
    c3 += __shfl_xor(c3, d);
  }
  int w = t >> 6;
  if ((t & 63) == 0) { part[w][0] = c0; part[w][1] = c1; part[w][2] = c2; part[w][3] = c3; }
  __syncthreads();
  if (t < 32) {
    int qd2 = t >> 2, e = t & 3;
    u32 r = part[qd2 * 2][e] + part[qd2 * 2 + 1][e];
    int p = B * 32 + t;
    sorted_id[r] = (u32)p;
    sx[r] = coords[2 * p];      // bitwise copies keep arithmetic exact
    sy[r] = coords[2 * p + 1];
    ss[r] = scores[p];
  }
}

// ---------------------------------------------------------------------------
// B: neighbor lists (triangular-tile lineage). Row-major per-point list
// (CAP=16 slots, 32B rows) + shared overflow (OVFC=12 -> exact up to 28
// earlier nbrs, the round-2-proven bound). d2<64 <=> sqrt(d2)<8 exactly in
// f32. Distance arithmetic unchanged.
// ---------------------------------------------------------------------------
__global__ __launch_bounds__(256) void k_nbr(const float* __restrict__ sx,
                                             const float* __restrict__ sy,
                                             u32* __restrict__ cnt,
                                             u32* __restrict__ cnt_ovf,
                                             u16* __restrict__ nbr,
                                             u16* __restrict__ nbr_ovf) {
  __shared__ float qx[128], qy[128];
  int b = blockIdx.x;
  int R = (int)((__fsqrt_rn(4.0f * (float)b + 1.0f) - 1.0f) * 0.5f);
  while ((R + 1) * (R + 2) <= b) ++R;
  while (R * (R + 1) > b) --R;
  int C = b - R * (R + 1);
  int t = threadIdx.x;
  int q0 = C << 7;
  int r = (R << 8) + t;
  if (t < 128) qx[t] = sx[q0 + t];
  else         qy[t - 128] = sy[q0 + t - 128];
  __syncthreads();

  float x = sx[r], y = sy[r];
  int jlim = 128;
  int dC = C - 2 * R;
  if (dC >= 0) {
    jlim = t - (dC << 7);
    if (jlim < 0) jlim = 0;
    if (jlim > 128) jlim = 128;
  }
  const float4* x4 = (const float4*)qx;
  const float4* y4 = (const float4*)qy;
  for (int jg = 0; jg < 4; ++jg) {
    int base = jg << 5;
    int v = jlim - base;
    u32 gm = (v >= 32) ? 0xFFFFFFFFu : ((v <= 0) ? 0u : ((1u << v) - 1u));
    u32 m = 0;
#pragma unroll
    for (int j4 = 0; j4 < 8; ++j4) {
      float4 xv = x4[(base >> 2) + j4];
      float4 yv = y4[(base >> 2) + j4];
      // mirror reference arithmetic: sub, mul, mul, add (no fma contraction)
      float dx0 = __fsub_rn(x, xv.x), dy0 = __fsub_rn(y, yv.x);
      float dx1 = __fsub_rn(x, xv.y), dy1 = __fsub_rn(y, yv.y);
      float dx2 = __fsub_rn(x, xv.z), dy2 = __fsub_rn(y, yv.z);
      float dx3 = __fsub_rn(x, xv.w), dy3 = __fsub_rn(y, yv.w);
      if (__fadd_rn(__fmul_rn(dx0, dx0), __fmul_rn(dy0, dy0)) < 64.0f) m |= 1u << (4 * j4 + 0);
      if (__fadd_rn(__fmul_rn(dx1, dx1), __fmul_rn(dy1, dy1)) < 64.0f) m |= 1u << (4 * j4 + 1);
      if (__fadd_rn(__fmul_rn(dx2, dx2), __fmul_rn(dy2, dy2)) < 64.0f) m |= 1u << (4 * j4 + 2);
      if (__fadd_rn(__fmul_rn(dx3, dx3), __fmul_rn(dy3, dy3)) < 64.0f) m |= 1u << (4 * j4 + 3);
    }
    m &= gm;
    while (m) {  // rare: lambda ~3 hits/point average
      int j2 = __builtin_ctz(m);
      m &= m - 1;
      int q = q0 + base + j2;   // strictly q < r (lower triangle)
      u32 sl = atomicAdd(&cnt[r], 1u);
      if (sl < CAP) nbr[((size_t)r << 4) + sl] = (u16)q;
      else {
        u32 so = atomicAdd(&cnt_ovf[r], 1u);
        if (so < OVFC) nbr_ovf[so * NPTS + r] = (u16)q;
      }
    }
  }
}

// ---------------------------------------------------------------------------
// C: monotone 3-state frontier fixpoint, ALL points at once.
// state: 0=undecided, 1=keep(final), 2=supp(final).
//   supp as soon as ANY earlier nbr is keep; keep when ALL earlier nbrs supp.
// Monotone undecided->final => chaotic reads always safe => 3 barrier-free
// passes per round (Gauss-Seidel chaining), one barrier/round. Min-rank
// undecided point always decidable => no-change round <=> exact fixpoint.
// Addresses packed 2 x u16 per VGPR (h[8][8] = 64 VGPR; fits the 128-VGPR
// cap for 16 waves/CU -- the round-2 version's int adr[8][12] spilled to
// scratch, which was the 3x slowdown). Decided-supp nbrs re-predicated to
// the neutral ZS slot => later reads broadcast (conflict-free) and whole
// 4-slot blocks skip via packed ==ZZ compares.
// ---------------------------------------------------------------------------
__global__ __launch_bounds__(1024) void k_nms(const u32* __restrict__ cnt,
                                              const u32* __restrict__ cnt_ovf,
                                              const u16* __restrict__ nbr,
                                              const u16* __restrict__ nbr_ovf,
                                              const u32* __restrict__ sorted_id,
                                              const float* __restrict__ ss,
                                              float* __restrict__ out) {
  __shared__ u8 state[NPTS + 4];
  __shared__ int flag[4];
  int t = threadIdx.x;

  // prefetch neighbor rows directly into the packed-h registers (32B/point)
  u32 h[8][8];
  u32 cn[8], co[8];
#pragma unroll
  for (int k = 0; k < 8; ++k) {
    int p = t + (k << 10);
    const uint4* rp = (const uint4*)(nbr + ((size_t)p << 4));
    uint4 v0 = rp[0], v1 = rp[1];
    h[k][0] = v0.x; h[k][1] = v0.y; h[k][2] = v0.z; h[k][3] = v0.w;
    h[k][4] = v1.x; h[k][5] = v1.y; h[k][6] = v1.z; h[k][7] = v1.w;
    cn[k] = cnt[p]; co[k] = cnt_ovf[p];
  }

  ((u32*)state)[t] = 0;
  ((u32*)state)[1024 + t] = 0;
  if (t == 0) state[NPTS] = 2;   // neutral slot: reads as SUPP
  if (t < 4) flag[t] = 0;
  __syncthreads();               // zeros visible before seeding writes

  u32 live = 0, conib = 0;
#pragma unroll
  for (int k = 0; k < 8; ++k) {
    int p = t + (k << 10);
    u32 c = cn[k] < (u32)CAP ? cn[k] : (u32)CAP;
#pragma unroll
    for (int j = 0; j < 8; ++j) {  // predicate in place: slots >= c -> ZS
      u32 hv = h[k][j];
      u32 lo = ((u32)(2 * j) < c) ? (hv & 0xFFFFu) : (u32)ZS;
      u32 hi = ((u32)(2 * j + 1) < c) ? (hv >> 16) : (u32)ZS;
      h[k][j] = lo | (hi << 16);
    }
    u32 cv = co[k] < (u32)OVFC ? co[k] : (u32)OVFC;
    conib |= cv << (4 * k);      // cv <= 12 fits a nibble
    if (cn[k] == 0 && co[k] == 0) state[p] = 1;  // no earlier nbrs: kept now
    else live |= 1u << k;
  }
  __syncthreads();               // seeds visible before round 1

#define SLOTS2(K, J) { \
    u32 hv = h[K][J]; \
    u32 a0 = hv & 0xFFFFu, a1 = hv >> 16; \
    u32 s0 = state[a0], s1 = state[a1]; \
    orv |= s0 | s1; andv &= s0 & s1; \
    hv = (s0 & 2u) ? ((hv & 0xFFFF0000u) | (u32)ZS) : hv; \
    hv = (s1 & 2u) ? ((hv & 0x0000FFFFu) | ((u32)ZS << 16)) : hv; \
    h[K][J] = hv; }

  for (int r = 1; r <= NPTS; ++r) {
    if (t == 0) flag[(r + 2) & 3] = 0;
    bool ch = false;
#pragma unroll
    for (int pass = 0; pass < 3; ++pass) {
      if (__any((int)(live != 0u))) {
#pragma unroll
        for (int k = 0; k < 8; ++k) {
          if (live & (1u << k)) {
            int p = t + (k << 10);
            u32 orv = 0, andv = 3u;
            if (h[k][0] != ZZ || h[k][1] != ZZ) { SLOTS2(k, 0) SLOTS2(k, 1) } else andv &= 2u;
            if (h[k][2] != ZZ || h[k][3] != ZZ) { SLOTS2(k, 2) SLOTS2(k, 3) } else andv &= 2u;
            if (h[k][4] != ZZ || h[k][5] != ZZ) { SLOTS2(k, 4) SLOTS2(k, 5) } else andv &= 2u;
            if (h[k][6] != ZZ || h[k][7] != ZZ) { SLOTS2(k, 6) SLOTS2(k, 7) } else andv &= 2u;
            u32 cv = (conib >> (4 * k)) & 15u;
            if (cv) {                     // ultra-rare overflow tail (cnt>16)
              for (u32 n = 0; n < cv; ++n) {
                u32 q = nbr_ovf[n * NPTS + (u32)p];
                u32 s = state[q];
                orv |= s; andv &= s;
              }
            }
            if (orv & 1u)       { state[p] = 2; live &= ~(1u << k); ch = true; }
            else if (andv & 2u) { state[p] = 1; live &= ~(1u << k); ch = true; }
          }
        }
      }
      asm volatile("" ::: "memory");  // no-cost fence: force re-reads across passes
    }
    if (ch) flag[r & 3] = 1;
    __syncthreads();
    if (flag[r & 3] == 0) break;  // full round w/o change <=> all decided
  }

  // epilogue: keep mask (original order) + suppressed scores (rank order)
  const uint4* sid4 = (const uint4*)sorted_id;
  const float4* ss4 = (const float4*)ss;
  for (int k4 = t; k4 < NPTS / 4; k4 += 1024) {
    uint4 sid = sid4[k4];
    float4 sv = ss4[k4];
    int k = k4 << 2;
    bool k0 = (state[k] == 1), k1 = (state[k + 1] == 1);
    bool k2 = (state[k + 2] == 1), k3 = (state[k + 3] == 1);
    out[sid.x] = k0 ? 1.0f : 0.0f;
    out[sid.y] = k1 ? 1.0f : 0.0f;
    out[sid.z] = k2 ? 1.0f : 0.0f;
    out[sid.w] = k3 ? 1.0f : 0.0f;
    float4 o;
    o.x = k0 ? sv.x : 0.0f;
    o.y = k1 ? sv.y : 0.0f;
    o.z = k2 ? sv.z : 0.0f;
    o.w = k3 ? sv.w : 0.0f;
    ((float4*)(out + NPTS))[k4] = o;
  }
}

// ---------------------------------------------------------------------------
extern "C" void kernel_launch(void* const* d_in, const int* in_sizes, int n_in,
                              void* d_out, int out_size, void* d_ws, size_t ws_size,
                              hipStream_t stream) {
  const float* coords = (const float*)d_in[0];  // [N,2]
  const float* scores = (const float*)d_in[1];  // [N]
  float* out = (float*)d_out;                   // [N keep | N suppressed scores]

  char* ws = (char*)d_ws;
  size_t off = 0;
  u16* nbr       = (u16*)(ws + off); off += (size_t)CAP * NPTS * 2;   // 256K
  u16* nbr_ovf   = (u16*)(ws + off); off += (size_t)OVFC * NPTS * 2;  // 192K
  u32* sorted_id = (u32*)(ws + off); off += (size_t)NPTS * 4;         //  32K
  float* sx      = (float*)(ws + off); off += (size_t)NPTS * 4;       //  32K
  float* sy      = (float*)(ws + off); off += (size_t)NPTS * 4;       //  32K
  float* ss      = (float*)(ws + off); off += (size_t)NPTS * 4;       //  32K
  u32* zero      = (u32*)(ws + off); off += (size_t)(2 * NPTS) * 4;   //  64K
  u32* cnt     = zero;
  u32* cnt_ovf = zero + NPTS;

  k_rank<<<256, 1024, 0, stream>>>(coords, scores, sorted_id, sx, sy, ss, zero);
  k_nbr<<<NTILES, 256, 0, stream>>>(sx, sy, cnt, cnt_ovf, nbr, nbr_ovf);
  k_nms<<<1, 1024, 0, stream>>>(cnt, cnt_ovf, nbr, nbr_ovf, sorted_id, ss, out);
}